// Round 4
// baseline (164.389 us; speedup 1.0000x reference)
//
#include <hip/hip_runtime.h>
#include <math.h>

// R4: latency attack. R1-R3 all pinned at ~47us across 1.6x changes in both
// VALU/batch and occupancy => not VALU-bound. T_wave ~9us vs ~1us of issue:
// waves park on the one-shot vmcnt(0) drain (queue-ballooned latency, nothing
// behind it). Fix = T3/T4: persistent waves (grid 1280 = 5 blk/CU LDS cap),
// double-buffered chunk pairs, counted s_waitcnt vmcnt(16) in steady state --
// next chunk's 16 DMA loads stay in flight across the compute phase; only the
// epilogue drains to 0. Keeps R3's 24-op/batch math (measured VALU floor
// ~17us => predict ~18-24us, VALUBusy 70-85%).
#define NPTS 21
#define FLB  63               // floats per batch per tensor
#define BPW  32               // batches per chunk (one chunk per wave-step)
#define THREADS 64            // one wave per block
#define TVEC (BPW * FLB / 4)  // 504 float4 per tensor chunk
#define FULLR (TVEC / 64)     // 7
#define TAILL (TVEC % 64)     // 56
#define KMAX 11               // points per lane (sub=0: 11, sub=1: 10)
#define GRID 1280             // 5 blocks/CU * 256 CU (exact LDS residency cap)

// direct global->LDS DMA, 16B per lane; lds ptr must be wave-uniform (HW adds lane*16)
__device__ __forceinline__ void async_cp16(const float* g, float* l) {
    __builtin_amdgcn_global_load_lds(
        (__attribute__((address_space(1))) void*)g,
        (__attribute__((address_space(3))) void*)l,
        16, 0, 0);
}

// 16 global_load_lds per chunk (8 pred + 8 targ), in fixed program order
__device__ __forceinline__ void stage_chunk(const float* __restrict__ pred,
                                            const float* __restrict__ targ,
                                            int chunk, float* lyb, float* lxb,
                                            int lane)
{
    const float* gp = pred + (size_t)chunk * (BPW * FLB);
    const float* gt = targ + (size_t)chunk * (BPW * FLB);
    #pragma unroll
    for (int j = 0; j < FULLR; ++j)
        async_cp16(gp + 4 * (j * 64 + lane), lyb + 4 * (j * 64));
    if (lane < TAILL)
        async_cp16(gp + 4 * (FULLR * 64 + lane), lyb + 4 * (FULLR * 64));
    #pragma unroll
    for (int j = 0; j < FULLR; ++j)
        async_cp16(gt + 4 * (j * 64 + lane), lxb + 4 * (j * 64));
    if (lane < TAILL)
        async_cp16(gt + 4 * (FULLR * 64 + lane), lxb + 4 * (FULLR * 64));
}

__global__ __launch_bounds__(THREADS, 3)
void pa_mpjpe(const float* __restrict__ pred,
              const float* __restrict__ targ,
              float* __restrict__ ws,
              int B)
{
    // double-buffered chunk pair: 2 x (8064 + 8064) = 32256 B -> 5 blocks/CU
    __shared__ __align__(16) float ly[2][BPW * FLB];   // pred
    __shared__ __align__(16) float lx[2][BPW * FLB];   // targ

    const int lane = threadIdx.x & 63;
    const int b    = lane & (BPW - 1);        // batch within chunk
    const int sub  = (lane >> 5) & 1;         // 0: even points, 1: odd points
    const int base = b * FLB;
    const int nch  = B / BPW;                 // 8192 chunks
    const int stride = gridDim.x;             // 1280

    // ---- prologue: fill the 2-deep pipeline ----
    int c  = blockIdx.x;
    stage_chunk(pred, targ, c, ly[0], lx[0], lane);
    int nc = c + stride;
    bool nif = (nc < nch);                    // next-in-flight?
    if (nif) stage_chunk(pred, targ, nc, ly[1], lx[1], lane);

    int cur = 0;
    float errsum = 0.0f;

    for (;;) {
        // wait for CURRENT chunk only; next chunk's 16 loads stay in flight
        if (nif) __builtin_amdgcn_s_waitcnt(0x4F70);   // vmcnt(16)
        else     __builtin_amdgcn_s_waitcnt(0x0F70);   // vmcnt(0), epilogue
        __builtin_amdgcn_sched_barrier(0);

        const float* Y = ly[cur];
        const float* X = lx[cur];

        // ---- pass 1: per-lane partial moments over points n = 2k + sub ----
        float py0[KMAX], py1[KMAX], py2[KMAX];
        float sy0=0.f, sy1=0.f, sy2=0.f, syy=0.f;
        float sx0=0.f, sx1=0.f, sx2=0.f;
        float m00=0,m01=0,m02=0, m10=0,m11=0,m12=0, m20=0,m21=0,m22=0;
        #pragma unroll
        for (int k = 0; k < KMAX; ++k) {
            const int n = 2 * k + sub;
            if (n < NPTS) {                            // only k=10,sub=1 masked
                const int o = base + 3 * n;
                float a = Y[o+0], e = Y[o+1], cc = Y[o+2];   // pred (Y)
                float u = X[o+0], v = X[o+1], x2 = X[o+2];   // targ (X)
                py0[k] = a; py1[k] = e; py2[k] = cc;
                sy0 += a; sy1 += e; sy2 += cc;
                syy = fmaf(a, a, fmaf(e, e, fmaf(cc, cc, syy)));
                sx0 += u; sx1 += v; sx2 += x2;
                m00 = fmaf(u,a,m00); m01 = fmaf(u,e,m01); m02 = fmaf(u,cc,m02);
                m10 = fmaf(v,a,m10); m11 = fmaf(v,e,m11); m12 = fmaf(v,cc,m12);
                m20 = fmaf(x2,a,m20); m21 = fmaf(x2,e,m21); m22 = fmaf(x2,cc,m22);
            } else {
                py0[k] = 0.f; py1[k] = 0.f; py2[k] = 0.f;
            }
        }

        // ---- combine the 2 lanes of each batch (xor 32) ----
        #define COMB(v) { v += __shfl_xor(v, 32, 64); }
        COMB(sy0) COMB(sy1) COMB(sy2) COMB(syy)
        COMB(sx0) COMB(sx1) COMB(sx2)
        COMB(m00) COMB(m01) COMB(m02)
        COMB(m10) COMB(m11) COMB(m12)
        COMB(m20) COMB(m21) COMB(m22)
        #undef COMB

        const float invN = 1.0f / (float)NPTS;
        float mux0 = sx0*invN, mux1 = sx1*invN, mux2 = sx2*invN;
        float muy0 = sy0*invN, muy1 = sy1*invN, muy2 = sy2*invN;
        float ny2  = syy - (sy0*sy0 + sy1*sy1 + sy2*sy2) * invN;   // ||Y0||_F^2
        float c00 = m00 - sx0*sy0*invN, c01 = m01 - sx0*sy1*invN, c02 = m02 - sx0*sy2*invN;
        float c10 = m10 - sx1*sy0*invN, c11 = m11 - sx1*sy1*invN, c12 = m12 - sx1*sy2*invN;
        float c20 = m20 - sx2*sy0*invN, c21 = m21 - sx2*sy1*invN, c22 = m22 - sx2*sy2*invN;

        // ---- orthogonal polar factor of A = Mc^T via det-scaled Newton ----
        float q00=c00, q01=c10, q02=c20,
              q10=c01, q11=c11, q12=c21,
              q20=c02, q21=c12, q22=c22;
        #pragma unroll
        for (int it = 0; it < 6; ++it) {
            float C00 = q11*q22 - q12*q21;
            float C01 = q12*q20 - q10*q22;
            float C02 = q10*q21 - q11*q20;
            float C10 = q02*q21 - q01*q22;
            float C11 = q00*q22 - q02*q20;
            float C12 = q01*q20 - q00*q21;
            float C20 = q01*q12 - q02*q11;
            float C21 = q02*q10 - q00*q12;
            float C22 = q00*q11 - q01*q10;
            float det = q00*C00 + q01*C01 + q02*C02;
            float ad  = fmaxf(fabsf(det), 1e-30f);
            float sdet = copysignf(ad, det);
            float g  = __expf(0.333333333f * __logf(ad));   // |det|^{1/3}
            float ha = 0.5f / g;
            float hb = 0.5f * g / sdet;
            q00 = ha*q00 + hb*C00; q01 = ha*q01 + hb*C01; q02 = ha*q02 + hb*C02;
            q10 = ha*q10 + hb*C10; q11 = ha*q11 + hb*C11; q12 = ha*q12 + hb*C12;
            q20 = ha*q20 + hb*C20; q21 = ha*q21 + hb*C21; q22 = ha*q22 + hb*C22;
        }

        float trP = q00*c00 + q01*c10 + q02*c20
                  + q10*c01 + q11*c11 + q12*c21
                  + q20*c02 + q21*c12 + q22*c22;
        float kk = trP / ny2;
        float r00=kk*q00, r01=kk*q01, r02=kk*q02;
        float r10=kk*q10, r11=kk*q11, r12=kk*q12;
        float r20=kk*q20, r21=kk*q21, r22=kk*q22;

        // ---- pass 2: per-joint error (targ re-read from LDS) ----
        #pragma unroll
        for (int k = 0; k < KMAX; ++k) {
            const int n = 2 * k + sub;
            if (n < NPTS) {
                const int o = base + 3 * n;
                float xa = X[o+0], xb = X[o+1], xc = X[o+2];
                float u = py0[k] - muy0, v = py1[k] - muy1, x2 = py2[k] - muy2;
                float z0 = fmaf(u, r00, fmaf(v, r10, fmaf(x2, r20, mux0))) - xa;
                float z1 = fmaf(u, r01, fmaf(v, r11, fmaf(x2, r21, mux1))) - xb;
                float z2 = fmaf(u, r02, fmaf(v, r12, fmaf(x2, r22, mux2))) - xc;
                errsum += sqrtf(fmaf(z0, z0, fmaf(z1, z1, z2*z2)));
            }
        }

        if (!nif) break;
        // ---- re-stage this (fully consumed) buffer with chunk + 2*stride ----
        int pc = nc + stride;
        bool pf = (pc < nch);
        __builtin_amdgcn_sched_barrier(0);   // keep re-stage after pass-2 reads
        if (pf) stage_chunk(pred, targ, pc, ly[cur], lx[cur], lane);
        c = nc; nc = pc; nif = pf; cur ^= 1;
    }

    // ---- full-wave reduce (all chunks of this block) -> one store ----
    #pragma unroll
    for (int off = 32; off > 0; off >>= 1) errsum += __shfl_down(errsum, off, 64);
    if (lane == 0) ws[blockIdx.x] = errsum;
}

// single block: reduce the per-block partials, write the final mean
__global__ __launch_bounds__(256)
void pa_reduce(const float* __restrict__ ws, float* __restrict__ out,
               int nblk, float inv_total)
{
    __shared__ float sw[4];
    float s = 0.0f;
    const float4* w4 = (const float4*)ws;
    const int n4 = nblk >> 2;
    for (int i = threadIdx.x; i < n4; i += 256) {
        float4 v = w4[i];
        s += (v.x + v.y) + (v.z + v.w);
    }
    for (int i = 4 * n4 + threadIdx.x; i < nblk; i += 256) s += ws[i];
    #pragma unroll
    for (int off = 32; off > 0; off >>= 1) s += __shfl_down(s, off, 64);
    if ((threadIdx.x & 63) == 0) sw[threadIdx.x >> 6] = s;
    __syncthreads();
    if (threadIdx.x == 0)
        out[0] = (sw[0] + sw[1] + sw[2] + sw[3]) * inv_total;
}

extern "C" void kernel_launch(void* const* d_in, const int* in_sizes, int n_in,
                              void* d_out, int out_size, void* d_ws, size_t ws_size,
                              hipStream_t stream)
{
    const float* pred = (const float*)d_in[0];   // pred_kp3d   [B,21,3] f32
    const float* targ = (const float*)d_in[1];   // target_kp3d [B,21,3] f32
    float* out = (float*)d_out;
    float* ws  = (float*)d_ws;

    int B = in_sizes[0] / FLB;                   // 262144
    int nch = B / BPW;                           // 8192 chunks
    int grid = (nch < GRID) ? nch : GRID;        // 1280 persistent blocks
    float inv_total = 1.0f / ((float)B * (float)NPTS);

    pa_mpjpe<<<grid, THREADS, 0, stream>>>(pred, targ, ws, B);
    pa_reduce<<<1, 256, 0, stream>>>(ws, out, grid, inv_total);
}

// Round 5
// 156.927 us; speedup vs baseline: 1.0476x; 1.0476x over previous
//
#include <hip/hip_runtime.h>
#include <math.h>

// R5: staging-path attack. Evidence from R1-R4: (a) warm-L3 runs (hbm~0) take
// the SAME time as cold runs => not BW-bound anywhere; (b) time-per-wave-chunk
// pinned at 8-11us across every block shape / wait structure; (c) the one
// invariant is global_load_lds staging (8-16 DMA per wave). R4's counted
// vmcnt(16) gave zero improvement (compiler must insert its own vmcnt(0)
// before ds_read of DMA-written LDS -- m131/m141 failure mode). Fix: drop
// lds-DMA entirely. Reg-staged transpose: coalesced global_load_dwordx4 ->
// VGPR -> ds_write_b128 (HK's reg-staging pattern; m13 proves plain loads
// sustain 6.3TB/s). Everything else identical to R3. No hand waitcnt at all:
// compiler inserts fine-grained vmcnt(N)-before-use (G7/m97 asm evidence).
#define NPTS 21
#define FLB  63               // floats per batch per tensor
#define BPW  32               // batches per wave
#define THREADS 64            // one wave per block
#define TVEC (BPW * FLB / 4)  // 504 float4 per tensor chunk
#define FULLR (TVEC / 64)     // 7
#define TAILL (TVEC % 64)     // 56
#define KMAX 11               // points per lane (sub=0: 11, sub=1: 10)

__global__ __launch_bounds__(THREADS, 4)   // cap VGPR at 128; LDS caps 10 blk/CU
void pa_mpjpe(const float* __restrict__ pred,
              const float* __restrict__ targ,
              float* __restrict__ ws,
              int B)
{
    __shared__ __align__(16) float ly[BPW * FLB];   // pred chunk, 8064 B
    __shared__ __align__(16) float lx[BPW * FLB];   // targ chunk, 8064 B

    const int lane = threadIdx.x & 63;
    const int b    = lane & (BPW - 1);        // batch within wave
    const int sub  = (lane >> 5) & 1;         // 0: even points, 1: odd points
    const int b0   = blockIdx.x * BPW;

    // ---- reg-staged coalesced loads: global -> VGPR (no lds-DMA) ----
    // b0*FLB*4 = blockIdx*8064 bytes -> 16B-aligned, float4 cast legal.
    const float4* gp = (const float4*)(pred + (size_t)b0 * FLB);
    const float4* gt = (const float4*)(targ + (size_t)b0 * FLB);
    float4 rp[FULLR + 1], rt[FULLR + 1];
    #pragma unroll
    for (int j = 0; j < FULLR; ++j) rp[j] = gp[j * 64 + lane];
    if (lane < TAILL)               rp[FULLR] = gp[FULLR * 64 + lane];
    #pragma unroll
    for (int j = 0; j < FULLR; ++j) rt[j] = gt[j * 64 + lane];
    if (lane < TAILL)               rt[FULLR] = gt[FULLR * 64 + lane];

    // ---- VGPR -> LDS transpose stores (per-lane ds_write_b128, conflict-free) ----
    {
        float4* wy = (float4*)ly;
        float4* wx = (float4*)lx;
        #pragma unroll
        for (int j = 0; j < FULLR; ++j) wy[j * 64 + lane] = rp[j];
        if (lane < TAILL)               wy[FULLR * 64 + lane] = rp[FULLR];
        #pragma unroll
        for (int j = 0; j < FULLR; ++j) wx[j * 64 + lane] = rt[j];
        if (lane < TAILL)               wx[FULLR * 64 + lane] = rt[FULLR];
    }
    // single wave: no barrier; compiler inserts lgkmcnt waits for the RAW dep.

    // ---- pass 1: per-lane partial moments over points n = 2k + sub ----
    float py0[KMAX], py1[KMAX], py2[KMAX];            // this lane's pred points
    float sy0=0.f, sy1=0.f, sy2=0.f, syy=0.f;
    float sx0=0.f, sx1=0.f, sx2=0.f;
    float m00=0,m01=0,m02=0, m10=0,m11=0,m12=0, m20=0,m21=0,m22=0;
    const int base = b * FLB;
    #pragma unroll
    for (int k = 0; k < KMAX; ++k) {
        const int n = 2 * k + sub;
        if (n < NPTS) {                                // only k=10,sub=1 masked
            const int o = base + 3 * n;
            float a = ly[o+0], e = ly[o+1], c = ly[o+2];   // pred (Y)
            float u = lx[o+0], v = lx[o+1], x2 = lx[o+2];  // targ (X)
            py0[k] = a; py1[k] = e; py2[k] = c;
            sy0 += a; sy1 += e; sy2 += c;
            syy = fmaf(a, a, fmaf(e, e, fmaf(c, c, syy)));
            sx0 += u; sx1 += v; sx2 += x2;
            m00 = fmaf(u,a,m00); m01 = fmaf(u,e,m01); m02 = fmaf(u,c,m02);
            m10 = fmaf(v,a,m10); m11 = fmaf(v,e,m11); m12 = fmaf(v,c,m12);
            m20 = fmaf(x2,a,m20); m21 = fmaf(x2,e,m21); m22 = fmaf(x2,c,m22);
        } else {
            py0[k] = 0.f; py1[k] = 0.f; py2[k] = 0.f;
        }
    }

    // ---- combine the 2 lanes of each batch (xor 32) ----
    #define COMB(v) { v += __shfl_xor(v, 32, 64); }
    COMB(sy0) COMB(sy1) COMB(sy2) COMB(syy)
    COMB(sx0) COMB(sx1) COMB(sx2)
    COMB(m00) COMB(m01) COMB(m02)
    COMB(m10) COMB(m11) COMB(m12)
    COMB(m20) COMB(m21) COMB(m22)
    #undef COMB

    const float invN = 1.0f / (float)NPTS;
    float mux0 = sx0*invN, mux1 = sx1*invN, mux2 = sx2*invN;
    float muy0 = sy0*invN, muy1 = sy1*invN, muy2 = sy2*invN;
    float ny2  = syy - (sy0*sy0 + sy1*sy1 + sy2*sy2) * invN;   // ||Y0||_F^2
    // centered cross-cov (rows: targ dims i, cols: pred dims j)
    float c00 = m00 - sx0*sy0*invN, c01 = m01 - sx0*sy1*invN, c02 = m02 - sx0*sy2*invN;
    float c10 = m10 - sx1*sy0*invN, c11 = m11 - sx1*sy1*invN, c12 = m12 - sx1*sy2*invN;
    float c20 = m20 - sx2*sy0*invN, c21 = m21 - sx2*sy1*invN, c22 = m22 - sx2*sy2*invN;

    // ---- orthogonal polar factor of A = Mc^T via det-scaled Newton ----
    float q00=c00, q01=c10, q02=c20,
          q10=c01, q11=c11, q12=c21,
          q20=c02, q21=c12, q22=c22;
    #pragma unroll
    for (int it = 0; it < 6; ++it) {
        float C00 = q11*q22 - q12*q21;
        float C01 = q12*q20 - q10*q22;
        float C02 = q10*q21 - q11*q20;
        float C10 = q02*q21 - q01*q22;
        float C11 = q00*q22 - q02*q20;
        float C12 = q01*q20 - q00*q21;
        float C20 = q01*q12 - q02*q11;
        float C21 = q02*q10 - q00*q12;
        float C22 = q00*q11 - q01*q10;
        float det = q00*C00 + q01*C01 + q02*C02;
        float ad  = fmaxf(fabsf(det), 1e-30f);
        float sdet = copysignf(ad, det);
        float g  = __expf(0.333333333f * __logf(ad));   // |det|^{1/3}
        float ha = 0.5f / g;                            // 0.5 * gamma
        float hb = 0.5f * g / sdet;                     // 0.5 * gamma^{-1} / det
        q00 = ha*q00 + hb*C00; q01 = ha*q01 + hb*C01; q02 = ha*q02 + hb*C02;
        q10 = ha*q10 + hb*C10; q11 = ha*q11 + hb*C11; q12 = ha*q12 + hb*C12;
        q20 = ha*q20 + hb*C20; q21 = ha*q21 + hb*C21; q22 = ha*q22 + hb*C22;
    }

    // tr(P) = <Q, A>_F with A = Mc^T (sum of singular values of Mc)
    float trP = q00*c00 + q01*c10 + q02*c20
              + q10*c01 + q11*c11 + q12*c21
              + q20*c02 + q21*c12 + q22*c22;
    float kk = trP / ny2;
    float r00=kk*q00, r01=kk*q01, r02=kk*q02;
    float r10=kk*q10, r11=kk*q11, r12=kk*q12;
    float r20=kk*q20, r21=kk*q21, r22=kk*q22;

    // ---- pass 2: per-joint error (targ re-read from LDS, pred from regs) ----
    float errsum = 0.0f;
    #pragma unroll
    for (int k = 0; k < KMAX; ++k) {
        const int n = 2 * k + sub;
        if (n < NPTS) {
            const int o = base + 3 * n;
            float xa = lx[o+0], xb = lx[o+1], xc = lx[o+2];
            float u = py0[k] - muy0, v = py1[k] - muy1, x2 = py2[k] - muy2;
            float z0 = fmaf(u, r00, fmaf(v, r10, fmaf(x2, r20, mux0))) - xa;
            float z1 = fmaf(u, r01, fmaf(v, r11, fmaf(x2, r21, mux1))) - xb;
            float z2 = fmaf(u, r02, fmaf(v, r12, fmaf(x2, r22, mux2))) - xc;
            errsum += sqrtf(fmaf(z0, z0, fmaf(z1, z1, z2*z2)));
        }
    }

    // ---- full-wave reduce (covers all 32 batches) -> one store per block ----
    #pragma unroll
    for (int off = 32; off > 0; off >>= 1) errsum += __shfl_down(errsum, off, 64);
    if (lane == 0) ws[blockIdx.x] = errsum;
}

// single block: reduce the per-block partials, write the final mean
__global__ __launch_bounds__(256)
void pa_reduce(const float* __restrict__ ws, float* __restrict__ out,
               int nblk, float inv_total)
{
    __shared__ float sw[4];
    float s = 0.0f;
    const float4* w4 = (const float4*)ws;
    const int n4 = nblk >> 2;                  // nblk divisible by 4
    for (int i = threadIdx.x; i < n4; i += 256) {
        float4 v = w4[i];
        s += (v.x + v.y) + (v.z + v.w);
    }
    #pragma unroll
    for (int off = 32; off > 0; off >>= 1) s += __shfl_down(s, off, 64);
    if ((threadIdx.x & 63) == 0) sw[threadIdx.x >> 6] = s;
    __syncthreads();
    if (threadIdx.x == 0)
        out[0] = (sw[0] + sw[1] + sw[2] + sw[3]) * inv_total;
}

extern "C" void kernel_launch(void* const* d_in, const int* in_sizes, int n_in,
                              void* d_out, int out_size, void* d_ws, size_t ws_size,
                              hipStream_t stream)
{
    const float* pred = (const float*)d_in[0];   // pred_kp3d   [B,21,3] f32
    const float* targ = (const float*)d_in[1];   // target_kp3d [B,21,3] f32
    float* out = (float*)d_out;
    float* ws  = (float*)d_ws;

    int B = in_sizes[0] / FLB;                   // 262144 (divisible by BPW)
    int grid = (B + BPW - 1) / BPW;              // 8192 blocks, 1 wave each
    float inv_total = 1.0f / ((float)B * (float)NPTS);

    pa_mpjpe<<<grid, THREADS, 0, stream>>>(pred, targ, ws, B);
    pa_reduce<<<1, 256, 0, stream>>>(ws, out, grid, inv_total);
}

// Round 6
// 151.053 us; speedup vs baseline: 1.0883x; 1.0389x over previous
//
#include <hip/hip_runtime.h>
#include <math.h>

// R6: residency attack, informed by the R0-R5 model fit:
//   time = (waves_retire / waves_resident) * lifetime,  lifetime ~9-10us fixed.
// R1 (8KB LDS) got 11.5 resident; R3/R5 (16KB) got 6. Staging path (DMA vs
// reg) is irrelevant (R5); spills are fatal (R5 WRITE=14.6MB). Fix: R0's
// single-buffer trick -- phase A: pred in LDS -> y regs + Y moments; phase B:
// targ OVERWRITES same 8064B buffer -> X moments + M + Newton + error.
// 8064B/wave -> 20 blocks/CU cap, one 16-reg staging set live at a time
// (peak ~110 VGPR, no spill), zero barriers (1 wave; sched_barrier(0) pins
// the read-before-overwrite order; HW DS pipe is in-order per wave).
#define NPTS 21
#define FLB  63               // floats per batch per tensor
#define BPW  32               // batches per wave
#define THREADS 64            // one wave per block
#define TVEC (BPW * FLB / 4)  // 504 float4 per tensor chunk
#define FULLR (TVEC / 64)     // 7
#define TAILL (TVEC % 64)     // 56
#define KMAX 11               // points per lane (sub=0: 11, sub=1: 10)

__global__ __launch_bounds__(THREADS, 4)   // VGPR cap 128
void pa_mpjpe(const float* __restrict__ pred,
              const float* __restrict__ targ,
              float* __restrict__ ws,
              int B)
{
    __shared__ __align__(16) float sb[BPW * FLB];   // ONE 8064 B buffer

    const int lane = threadIdx.x & 63;
    const int b    = lane & (BPW - 1);        // batch within wave
    const int sub  = (lane >> 5) & 1;         // 0: even points, 1: odd points
    const int b0   = blockIdx.x * BPW;
    const int base = b * FLB;
    float4* w4 = (float4*)sb;

    // ================= phase A: PRED =================
    {   // reg-stage pred -> LDS (one 16-reg set; dead after the writes)
        const float4* gp = (const float4*)(pred + (size_t)b0 * FLB);
        float4 r[FULLR + 1];
        #pragma unroll
        for (int j = 0; j < FULLR; ++j) r[j] = gp[j * 64 + lane];
        if (lane < TAILL)               r[FULLR] = gp[FULLR * 64 + lane];
        #pragma unroll
        for (int j = 0; j < FULLR; ++j) w4[j * 64 + lane] = r[j];
        if (lane < TAILL)               w4[FULLR * 64 + lane] = r[FULLR];
    }

    // pass A: this lane's pred points -> regs, Y moments
    float py0[KMAX], py1[KMAX], py2[KMAX];
    float sy0=0.f, sy1=0.f, sy2=0.f, syy=0.f;
    #pragma unroll
    for (int k = 0; k < KMAX; ++k) {
        const int n = 2 * k + sub;
        if (n < NPTS) {                        // only k=10,sub=1 masked
            const int o = base + 3 * n;
            float a = sb[o+0], e = sb[o+1], c = sb[o+2];
            py0[k] = a; py1[k] = e; py2[k] = c;
            sy0 += a; sy1 += e; sy2 += c;
            syy = fmaf(a, a, fmaf(e, e, fmaf(c, c, syy)));
        } else {
            py0[k] = 0.f; py1[k] = 0.f; py2[k] = 0.f;
        }
    }

    // pin order: NOTHING below (targ ds_writes) may move above this point
    __builtin_amdgcn_sched_barrier(0);

    // ================= phase B: TARG (same buffer) =================
    {   // reg-stage targ -> LDS (fresh 16-reg set; y regs stay live)
        const float4* gt = (const float4*)(targ + (size_t)b0 * FLB);
        float4 r[FULLR + 1];
        #pragma unroll
        for (int j = 0; j < FULLR; ++j) r[j] = gt[j * 64 + lane];
        if (lane < TAILL)               r[FULLR] = gt[FULLR * 64 + lane];
        #pragma unroll
        for (int j = 0; j < FULLR; ++j) w4[j * 64 + lane] = r[j];
        if (lane < TAILL)               w4[FULLR * 64 + lane] = r[FULLR];
    }

    // pass B1: X moments + raw cross-covariance (y from regs)
    float sx0=0.f, sx1=0.f, sx2=0.f;
    float m00=0,m01=0,m02=0, m10=0,m11=0,m12=0, m20=0,m21=0,m22=0;
    #pragma unroll
    for (int k = 0; k < KMAX; ++k) {
        const int n = 2 * k + sub;
        if (n < NPTS) {
            const int o = base + 3 * n;
            float u = sb[o+0], v = sb[o+1], x2 = sb[o+2];  // targ (X)
            float a = py0[k], e = py1[k], c = py2[k];      // pred (Y)
            sx0 += u; sx1 += v; sx2 += x2;
            m00 = fmaf(u,a,m00); m01 = fmaf(u,e,m01); m02 = fmaf(u,c,m02);
            m10 = fmaf(v,a,m10); m11 = fmaf(v,e,m11); m12 = fmaf(v,c,m12);
            m20 = fmaf(x2,a,m20); m21 = fmaf(x2,e,m21); m22 = fmaf(x2,c,m22);
        }
    }

    // ---- combine the 2 lanes of each batch (xor 32) ----
    #define COMB(v) { v += __shfl_xor(v, 32, 64); }
    COMB(sy0) COMB(sy1) COMB(sy2) COMB(syy)
    COMB(sx0) COMB(sx1) COMB(sx2)
    COMB(m00) COMB(m01) COMB(m02)
    COMB(m10) COMB(m11) COMB(m12)
    COMB(m20) COMB(m21) COMB(m22)
    #undef COMB

    const float invN = 1.0f / (float)NPTS;
    float mux0 = sx0*invN, mux1 = sx1*invN, mux2 = sx2*invN;
    float muy0 = sy0*invN, muy1 = sy1*invN, muy2 = sy2*invN;
    float ny2  = syy - (sy0*sy0 + sy1*sy1 + sy2*sy2) * invN;   // ||Y0||_F^2
    // centered cross-cov (rows: targ dims i, cols: pred dims j)
    float c00 = m00 - sx0*sy0*invN, c01 = m01 - sx0*sy1*invN, c02 = m02 - sx0*sy2*invN;
    float c10 = m10 - sx1*sy0*invN, c11 = m11 - sx1*sy1*invN, c12 = m12 - sx1*sy2*invN;
    float c20 = m20 - sx2*sy0*invN, c21 = m21 - sx2*sy1*invN, c22 = m22 - sx2*sy2*invN;

    // ---- orthogonal polar factor of A = Mc^T via det-scaled Newton ----
    float q00=c00, q01=c10, q02=c20,
          q10=c01, q11=c11, q12=c21,
          q20=c02, q21=c12, q22=c22;
    #pragma unroll
    for (int it = 0; it < 6; ++it) {
        float C00 = q11*q22 - q12*q21;
        float C01 = q12*q20 - q10*q22;
        float C02 = q10*q21 - q11*q20;
        float C10 = q02*q21 - q01*q22;
        float C11 = q00*q22 - q02*q20;
        float C12 = q01*q20 - q00*q21;
        float C20 = q01*q12 - q02*q11;
        float C21 = q02*q10 - q00*q12;
        float C22 = q00*q11 - q01*q10;
        float det = q00*C00 + q01*C01 + q02*C02;
        float ad  = fmaxf(fabsf(det), 1e-30f);
        float sdet = copysignf(ad, det);
        float g  = __expf(0.333333333f * __logf(ad));   // |det|^{1/3}
        float ha = 0.5f / g;                            // 0.5 * gamma
        float hb = 0.5f * g / sdet;                     // 0.5 * gamma^{-1} / det
        q00 = ha*q00 + hb*C00; q01 = ha*q01 + hb*C01; q02 = ha*q02 + hb*C02;
        q10 = ha*q10 + hb*C10; q11 = ha*q11 + hb*C11; q12 = ha*q12 + hb*C12;
        q20 = ha*q20 + hb*C20; q21 = ha*q21 + hb*C21; q22 = ha*q22 + hb*C22;
    }

    // tr(P) = <Q, A>_F with A = Mc^T (sum of singular values of Mc)
    float trP = q00*c00 + q01*c10 + q02*c20
              + q10*c01 + q11*c11 + q12*c21
              + q20*c02 + q21*c12 + q22*c22;
    float kk = trP / ny2;
    float r00=kk*q00, r01=kk*q01, r02=kk*q02;
    float r10=kk*q10, r11=kk*q11, r12=kk*q12;
    float r20=kk*q20, r21=kk*q21, r22=kk*q22;

    // pass B2: per-joint error (targ still in LDS, pred from regs)
    float errsum = 0.0f;
    #pragma unroll
    for (int k = 0; k < KMAX; ++k) {
        const int n = 2 * k + sub;
        if (n < NPTS) {
            const int o = base + 3 * n;
            float xa = sb[o+0], xb = sb[o+1], xc = sb[o+2];
            float u = py0[k] - muy0, v = py1[k] - muy1, x2 = py2[k] - muy2;
            float z0 = fmaf(u, r00, fmaf(v, r10, fmaf(x2, r20, mux0))) - xa;
            float z1 = fmaf(u, r01, fmaf(v, r11, fmaf(x2, r21, mux1))) - xb;
            float z2 = fmaf(u, r02, fmaf(v, r12, fmaf(x2, r22, mux2))) - xc;
            errsum += sqrtf(fmaf(z0, z0, fmaf(z1, z1, z2*z2)));
        }
    }

    // ---- full-wave reduce (covers all 32 batches) -> one store per block ----
    #pragma unroll
    for (int off = 32; off > 0; off >>= 1) errsum += __shfl_down(errsum, off, 64);
    if (lane == 0) ws[blockIdx.x] = errsum;
}

// single block: reduce the per-block partials, write the final mean
__global__ __launch_bounds__(256)
void pa_reduce(const float* __restrict__ ws, float* __restrict__ out,
               int nblk, float inv_total)
{
    __shared__ float sw[4];
    float s = 0.0f;
    const float4* w4 = (const float4*)ws;
    const int n4 = nblk >> 2;                  // nblk divisible by 4
    for (int i = threadIdx.x; i < n4; i += 256) {
        float4 v = w4[i];
        s += (v.x + v.y) + (v.z + v.w);
    }
    #pragma unroll
    for (int off = 32; off > 0; off >>= 1) s += __shfl_down(s, off, 64);
    if ((threadIdx.x & 63) == 0) sw[threadIdx.x >> 6] = s;
    __syncthreads();
    if (threadIdx.x == 0)
        out[0] = (sw[0] + sw[1] + sw[2] + sw[3]) * inv_total;
}

extern "C" void kernel_launch(void* const* d_in, const int* in_sizes, int n_in,
                              void* d_out, int out_size, void* d_ws, size_t ws_size,
                              hipStream_t stream)
{
    const float* pred = (const float*)d_in[0];   // pred_kp3d   [B,21,3] f32
    const float* targ = (const float*)d_in[1];   // target_kp3d [B,21,3] f32
    float* out = (float*)d_out;
    float* ws  = (float*)d_ws;

    int B = in_sizes[0] / FLB;                   // 262144 (divisible by BPW)
    int grid = (B + BPW - 1) / BPW;              // 8192 blocks, 1 wave each
    float inv_total = 1.0f / ((float)B * (float)NPTS);

    pa_mpjpe<<<grid, THREADS, 0, stream>>>(pred, targ, ws, B);
    pa_reduce<<<1, 256, 0, stream>>>(ws, out, grid, inv_total);
}